// Round 8
// baseline (95.279 us; speedup 1.0000x reference)
//
#include <hip/hip_runtime.h>
#include <hip/hip_bf16.h>

// out[b,n] = 2*x.y - ||x_b||^2 - ||y_n||^2
// x: [M=4096, K=1024] f32   y: [N=8192, K=1024] f32   out: [M, N] f32
//
// Round 8: persistent 2-tile blocks. Grid = 256 (1 block/CU, ONE round);
// each block does tiles (tm,tn) and (tm,tn+16) sequentially, sharing the
// A panel. Tile-1's prologue staging is issued BEFORE tile-0's epilogue
// stores, hiding the staging latency under the store burst. K-loop is the
// round-6 verified 8-phase template, unrolled x2 (compile-time LDS bases).
// T2 swizzle (conflicts=0), XCD-aware pair mapping, setprio, counted vmcnt.

typedef __attribute__((ext_vector_type(8)))  short bf16x8;
typedef __attribute__((ext_vector_type(4))) float f32x4;

#define BM 256
#define BN 256
#define KDIM 1024
#define NT 16                  // K-tiles of BK=64

__device__ __forceinline__ short f2bf(float f) {
    __hip_bfloat16 h = __float2bfloat16(f);
    return *reinterpret_cast<short*>(&h);
}

__device__ __forceinline__ void gld16(const short* g, short* l) {
    __builtin_amdgcn_global_load_lds(
        (const __attribute__((address_space(1))) unsigned int*)g,
        (__attribute__((address_space(3))) unsigned int*)l,
        16, 0, 0);
}

#define BAR()   asm volatile("s_barrier" ::: "memory")
#define LGKM0() asm volatile("s_waitcnt lgkmcnt(0)" ::: "memory")

// ---------------- prep: f32 -> bf16 + row squared-norms -------------------
__global__ __launch_bounds__(256) void prep_kernel(
    const float* __restrict__ x, const float* __restrict__ y,
    short* __restrict__ xb, short* __restrict__ yb,
    float* __restrict__ xsq, float* __restrict__ ysq, int M, int N)
{
    int row = blockIdx.x;
    const float* src;
    short* dst;
    float* nrm;
    if (row < M) {
        src = x + (size_t)row * KDIM;
        dst = xb + (size_t)row * KDIM;
        nrm = xsq + row;
    } else {
        int r = row - M;
        src = y + (size_t)r * KDIM;
        dst = yb + (size_t)r * KDIM;
        nrm = ysq + r;
    }
    int t = threadIdx.x;                       // 256 threads, 4 floats each
    float4 v = ((const float4*)src)[t];
    float s = v.x * v.x + v.y * v.y + v.z * v.z + v.w * v.w;
    short4 o;
    o.x = f2bf(v.x); o.y = f2bf(v.y); o.z = f2bf(v.z); o.w = f2bf(v.w);
    ((short4*)dst)[t] = o;

    #pragma unroll
    for (int off = 32; off > 0; off >>= 1) s += __shfl_down(s, off, 64);
    __shared__ float red[4];
    if ((t & 63) == 0) red[t >> 6] = s;
    __syncthreads();
    if (t == 0) *nrm = red[0] + red[1] + red[2] + red[3];
}

// ---------------- main persistent 2-tile 8-phase bf16 GEMM ----------------
// LDS: A[2buf][2half][128][64] shorts (0..32767), B same (32768..65535).
__global__ __launch_bounds__(512, 2) void gemm_l2(
    const short* __restrict__ xb, const short* __restrict__ yb,
    const float* __restrict__ xsq, const float* __restrict__ ysq,
    float* __restrict__ out, int M, int N)
{
    __shared__ __align__(16) short lds[65536];   // 128 KiB

    // pair mapping: 256 blocks -> (tm, tnp); tiles (tm,tnp) and (tm,tnp+16).
    // XCD-aware: blocks sharing an XCD cover a 4(tm) x 8(tnp) region.
    const int p   = blockIdx.x;
    const int xcd = p & 7, q = p >> 3;          // q in [0,32)
    const int tm  = (xcd >> 1) * 4 + (q >> 3);  // [0,16)
    const int tnp = (xcd & 1) * 8 + (q & 7);    // [0,16)

    const int tid  = threadIdx.x;       // 512 threads = 8 waves
    const int wid  = tid >> 6;
    const int lane = tid & 63;
    const int wm   = wid >> 2;          // 0..1
    const int wn   = wid & 3;           // 0..3
    const int l15  = lane & 15;
    const int hi   = lane >> 4;         // 0..3
    const int s8   = lane & 7;

    // ---- staging (verified swizzle): dest LINEAR, global source 16B-block
    // pre-permuted: cbs = (lane&7) ^ ((lane>>3)&7). ----
    const int r8  = lane >> 3;
    const int cbs = s8 ^ (r8 & 7);
    const short* aBase = xb + (size_t)(tm * BM + wid * 16 + r8) * KDIM + cbs * 8;
    const size_t bRowOff = (size_t)(wid * 16 + r8) * KDIM + cbs * 8;
    const int dstBase = wid * 1024 + lane * 8;

    #define STAGE_A_TO(bofs, kt, h) do {                                       \
        const short* g_ = aBase + (size_t)(h) * 128 * KDIM + (size_t)(kt) * 64; \
        short* d_ = &lds[(bofs) + (h) * 8192 + dstBase];                       \
        gld16(g_, d_); gld16(g_ + 8 * KDIM, d_ + 512);                         \
    } while (0)
    #define STAGE_B_TO(bofs, kt, h) do {                                       \
        const short* g_ = bB + (size_t)(h) * 128 * KDIM + (size_t)(kt) * 64;   \
        short* d_ = &lds[32768 + (bofs) + (h) * 8192 + dstBase];               \
        gld16(g_, d_); gld16(g_ + 8 * KDIM, d_ + 512);                         \
    } while (0)
    // prologue FIFO: A0,B0,A1,B1 of tile kt0 into buf0; A0,B0 of kt0+1 -> buf1
    #define PROLOGUE6() do {                                                   \
        STAGE_A_TO(0, 0, 0); STAGE_B_TO(0, 0, 0);                              \
        STAGE_A_TO(0, 0, 1); STAGE_B_TO(0, 0, 1);                              \
        STAGE_A_TO(16384, 1, 0); STAGE_B_TO(16384, 1, 0);                      \
    } while (0)

    // ---- fragment read offsets (shorts); phys block = (ks*4+hi) ^ s8 ----
    int aro[4], bro[2], xk[2];
    #pragma unroll
    for (int i = 0; i < 4; ++i) aro[i] = (wm * 64 + i * 16 + l15) * 64;
    #pragma unroll
    for (int j = 0; j < 2; ++j) bro[j] = (wn * 32 + j * 16 + l15) * 64;
    xk[0] = ((0 + hi) ^ s8) * 8;
    xk[1] = ((4 + hi) ^ s8) * 8;

    #define MFMA_Q(mq, nq) do {                                              \
        _Pragma("unroll") for (int ks = 0; ks < 2; ++ks)                     \
        _Pragma("unroll") for (int i = 0; i < 4; ++i)                        \
        _Pragma("unroll") for (int j = 0; j < 2; ++j)                        \
            acc[mq][i][nq][j] = __builtin_amdgcn_mfma_f32_16x16x32_bf16(     \
                aF[ks][i], bF[nq][ks][j], acc[mq][i][nq][j], 0, 0, 0);       \
    } while (0)

    // one K-tile, 4 phases, compile-time buffer bases AB (this) / NB (other)
    #define KTILE(s, AB, NB) do {                                            \
        /* p0: q(0,0) — read A0(8) + B0(4); stage A1(s+1) */                 \
        _Pragma("unroll") for (int ks = 0; ks < 2; ++ks) {                   \
            _Pragma("unroll") for (int i = 0; i < 4; ++i)                    \
                aF[ks][i] = *(const bf16x8*)&lds[(AB) + aro[i] + xk[ks]];    \
            _Pragma("unroll") for (int j = 0; j < 2; ++j)                    \
                bF[0][ks][j] = *(const bf16x8*)&lds[32768 + (AB) + bro[j] + xk[ks]]; \
        }                                                                    \
        if ((s) + 1 < NT) STAGE_A_TO(NB, (s) + 1, 1);                        \
        asm volatile("s_waitcnt lgkmcnt(8)" ::: "memory");                   \
        BAR();                                                               \
        LGKM0();                                                             \
        __builtin_amdgcn_sched_barrier(0);                                   \
        __builtin_amdgcn_s_setprio(1);                                       \
        MFMA_Q(0, 0);                                                        \
        __builtin_amdgcn_s_setprio(0);                                       \
        if ((s) < NT - 1) { asm volatile("s_waitcnt vmcnt(6)" ::: "memory"); } \
        else              { asm volatile("s_waitcnt vmcnt(0)" ::: "memory"); } \
        BAR();                                                               \
        /* p1: q(0,1) — read B1(4); stage B1(s+1) */                         \
        _Pragma("unroll") for (int ks = 0; ks < 2; ++ks)                     \
            _Pragma("unroll") for (int j = 0; j < 2; ++j)                    \
                bF[1][ks][j] = *(const bf16x8*)&lds[32768 + (AB) + 8192 + bro[j] + xk[ks]]; \
        if ((s) + 1 < NT) STAGE_B_TO(NB, (s) + 1, 1);                        \
        BAR();                                                               \
        LGKM0();                                                             \
        __builtin_amdgcn_sched_barrier(0);                                   \
        __builtin_amdgcn_s_setprio(1);                                       \
        MFMA_Q(0, 1);                                                        \
        __builtin_amdgcn_s_setprio(0);                                       \
        BAR();                                                               \
        /* p2: q(1,0) — read A1(8); stage A0(s+2) */                         \
        _Pragma("unroll") for (int ks = 0; ks < 2; ++ks)                     \
            _Pragma("unroll") for (int i = 0; i < 4; ++i)                    \
                aF[ks][i] = *(const bf16x8*)&lds[(AB) + 8192 + aro[i] + xk[ks]]; \
        if ((s) + 2 < NT) STAGE_A_TO(AB, (s) + 2, 0);                        \
        BAR();                                                               \
        LGKM0();                                                             \
        __builtin_amdgcn_sched_barrier(0);                                   \
        __builtin_amdgcn_s_setprio(1);                                       \
        MFMA_Q(1, 0);                                                        \
        __builtin_amdgcn_s_setprio(0);                                       \
        BAR();                                                               \
        /* p3: q(1,1) — no reads; stage B0(s+2) */                           \
        if ((s) + 2 < NT) STAGE_B_TO(AB, (s) + 2, 0);                        \
        __builtin_amdgcn_s_setprio(1);                                       \
        MFMA_Q(1, 1);                                                        \
        __builtin_amdgcn_s_setprio(0);                                       \
        if ((s) < NT - 2)       { asm volatile("s_waitcnt vmcnt(8)" ::: "memory"); } \
        else if ((s) == NT - 2) { asm volatile("s_waitcnt vmcnt(4)" ::: "memory"); } \
        BAR();                                                               \
    } while (0)

    const short* bB;                 // current tile's B staging base
    f32x4 acc[2][4][2][2];           // [mq][i][nq][j]
    bf16x8 aF[2][4];                 // [ks][i]
    bf16x8 bF[2][2][2];              // [nq][ks][j]

    // ---- tile 0 prologue ----
    bB = yb + (size_t)(tnp * BN) * KDIM + bRowOff;
    PROLOGUE6();
    asm volatile("s_waitcnt vmcnt(8)" ::: "memory");
    BAR();

    #pragma unroll
    for (int tile = 0; tile < 2; ++tile) {
        const int tn = tnp + tile * 16;
        // zero acc
        #pragma unroll
        for (int a0 = 0; a0 < 2; ++a0)
            #pragma unroll
            for (int a1 = 0; a1 < 4; ++a1)
                #pragma unroll
                for (int a2 = 0; a2 < 2; ++a2)
                    #pragma unroll
                    for (int a3 = 0; a3 < 2; ++a3)
                        acc[a0][a1][a2][a3] = (f32x4){0.f, 0.f, 0.f, 0.f};

        // ---- K loop, unrolled x2 (even tile -> buf0, odd -> buf1) ----
        for (int s2 = 0; s2 < NT; s2 += 2) {
            KTILE(s2,     0,     16384);
            KTILE(s2 + 1, 16384, 0);
        }
        // loop exits with no outstanding vmem, all waves past final BAR.

        // ---- issue NEXT tile's prologue before this epilogue ----
        if (tile == 0) {
            bB = yb + (size_t)((tnp + 16) * BN) * KDIM + bRowOff;
            PROLOGUE6();
        }

        // ---- epilogue: out = 2*acc - xsq[row] - ysq[col] ----
        // C/D layout (16x16): col = lane&15, row = (lane>>4)*4 + reg
        #pragma unroll
        for (int mq = 0; mq < 2; ++mq)
            #pragma unroll
            for (int i = 0; i < 4; ++i) {
                int r0 = tm * BM + mq * 128 + wm * 64 + i * 16 + hi * 4;
                #pragma unroll
                for (int nq = 0; nq < 2; ++nq)
                    #pragma unroll
                    for (int j = 0; j < 2; ++j) {
                        int c = tn * BN + nq * 128 + wn * 32 + j * 16 + l15;
                        float ysv = ysq[c];
                        #pragma unroll
                        for (int r = 0; r < 4; ++r) {
                            int row = r0 + r;
                            out[(size_t)row * N + c] =
                                2.0f * acc[mq][i][nq][j][r] - xsq[row] - ysv;
                        }
                    }
            }

        if (tile == 0) {
            // drain epilogue stores + ensure tile-1's first halves resident
            asm volatile("s_waitcnt vmcnt(0)" ::: "memory");
            BAR();
        }
    }
}

// ---------------- fallback (shape/ws mismatch): exact f32 -----------------
__global__ __launch_bounds__(256) void fallback_l2(
    const float* __restrict__ x, const float* __restrict__ y,
    float* __restrict__ out, int M, int N, int K)
{
    int tx = threadIdx.x & 15, ty = threadIdx.x >> 4;
    int row = blockIdx.y * 16 + ty;
    int col = blockIdx.x * 16 + tx;
    __shared__ float xs[16][17], ys[16][17];
    float s = 0.f;
    for (int k0 = 0; k0 < K; k0 += 16) {
        xs[ty][tx] = x[(size_t)row * K + k0 + tx];
        ys[ty][tx] = y[(size_t)(blockIdx.x * 16 + ty) * K + k0 + tx];
        __syncthreads();
        #pragma unroll
        for (int kk = 0; kk < 16; ++kk) {
            float d = xs[ty][kk] - ys[tx][kk];
            s += d * d;
        }
        __syncthreads();
    }
    out[(size_t)row * N + col] = -s;
}

extern "C" void kernel_launch(void* const* d_in, const int* in_sizes, int n_in,
                              void* d_out, int out_size, void* d_ws, size_t ws_size,
                              hipStream_t stream) {
    const float* x = (const float*)d_in[0];
    const float* y = (const float*)d_in[1];
    float* out = (float*)d_out;
    const int M = in_sizes[0] / KDIM;   // 4096
    const int N = in_sizes[1] / KDIM;   // 8192

    size_t need = (size_t)(M + N) * KDIM * sizeof(short)
                + (size_t)(M + N) * sizeof(float) + 256;
    if (ws_size >= need && M == 4096 && N == 8192) {
        char* w = (char*)d_ws;
        short* xb  = (short*)w;
        short* yb  = xb + (size_t)M * KDIM;
        float* xsq = (float*)(yb + (size_t)N * KDIM);
        float* ysq = xsq + M;

        prep_kernel<<<M + N, 256, 0, stream>>>(x, y, xb, yb, xsq, ysq, M, N);
        gemm_l2<<<256, 512, 0, stream>>>(xb, yb, xsq, ysq, out, M, N);
    } else {
        dim3 g(N / 16, M / 16);
        fallback_l2<<<g, 256, 0, stream>>>(x, y, out, M, N, KDIM);
    }
}

// Round 10
// 66.427 us; speedup vs baseline: 1.4343x; 1.4343x over previous
//
#include <hip/hip_runtime.h>
#include <hip/hip_bf16.h>

// out[b,n] = 2*x.y - ||x_b||^2 - ||y_n||^2
// x: [M=4096, K=1024] f32   y: [N=8192, K=1024] f32   out: [M, N] f32
//
// Round 10: INT8 MFMA (round-9 + staging-offset fix: second 8-row chunk is
// +1024 B, not +2048 B). Per-row symmetric quant (scale = amax/127, exact
// f32 row norms). GEMM = round-6's verified 8-phase 256x256 template at
// BK=128 bytes (mfma_i32_16x16x64_i8): half the K-tiles/reads/bytes/barriers
// of bf16. out = (2*sx[b])*sy[n]*dot_i32 - xsq[b] - ysq[n]; |dot| < 2^24 so
// the int->float convert is exact. T2 swizzle, XCD 8x8, counted vmcnt, setprio.

typedef __attribute__((ext_vector_type(4))) int i32x4;

#define BM 256
#define BN 256
#define KD 1024                // K elements (= bytes per i8 row)
#define NT 8                   // K-tiles of BK=128

__device__ __forceinline__ void gld16(const void* g, void* l) {
    __builtin_amdgcn_global_load_lds(
        (const __attribute__((address_space(1))) unsigned int*)g,
        (__attribute__((address_space(3))) unsigned int*)l,
        16, 0, 0);
}

#define BAR()   asm volatile("s_barrier" ::: "memory")
#define LGKM0() asm volatile("s_waitcnt lgkmcnt(0)" ::: "memory")

// ------------- prep: per-row amax + sumsq + i8 quantize -------------------
__global__ __launch_bounds__(256) void prep_q(
    const float* __restrict__ x, const float* __restrict__ y,
    signed char* __restrict__ xq, signed char* __restrict__ yq,
    float* __restrict__ sx, float* __restrict__ sy,
    float* __restrict__ xsq, float* __restrict__ ysq, int M, int N)
{
    int row = blockIdx.x;
    const float* src;
    signed char* dst;
    float* nrm;
    float* scl;
    float sfac;
    if (row < M) {
        src = x + (size_t)row * KD; dst = xq + (size_t)row * KD;
        nrm = xsq + row; scl = sx + row; sfac = 2.0f;   // fold the 2* here
    } else {
        int r = row - M;
        src = y + (size_t)r * KD; dst = yq + (size_t)r * KD;
        nrm = ysq + r; scl = sy + r; sfac = 1.0f;
    }
    int t = threadIdx.x;                        // 256 threads, 4 floats each
    float4 v = ((const float4*)src)[t];
    float ss = v.x * v.x + v.y * v.y + v.z * v.z + v.w * v.w;
    float am = fmaxf(fmaxf(fabsf(v.x), fabsf(v.y)),
                     fmaxf(fabsf(v.z), fabsf(v.w)));
    #pragma unroll
    for (int off = 32; off > 0; off >>= 1) {
        ss += __shfl_down(ss, off, 64);
        am = fmaxf(am, __shfl_down(am, off, 64));
    }
    __shared__ float rs[4], rm[4];
    if ((t & 63) == 0) { rs[t >> 6] = ss; rm[t >> 6] = am; }
    __syncthreads();
    float tots = rs[0] + rs[1] + rs[2] + rs[3];
    float totm = fmaxf(fmaxf(rm[0], rm[1]), fmaxf(rm[2], rm[3]));
    float inv = totm > 0.0f ? 127.0f / totm : 0.0f;

    int q0 = (int)rintf(v.x * inv), q1 = (int)rintf(v.y * inv);
    int q2 = (int)rintf(v.z * inv), q3 = (int)rintf(v.w * inv);
    q0 = max(-127, min(127, q0)); q1 = max(-127, min(127, q1));
    q2 = max(-127, min(127, q2)); q3 = max(-127, min(127, q3));
    int packed = (q0 & 255) | ((q1 & 255) << 8) |
                 ((q2 & 255) << 16) | ((q3 & 255) << 24);
    ((int*)dst)[t] = packed;
    if (t == 0) { *nrm = tots; *scl = sfac * totm / 127.0f; }
}

// ------------- main 256x256 8-phase i8 MFMA GEMM --------------------------
// LDS bytes: A[2buf][2half][128 rows][128 B] = 0..65535, B same 65536..131071.
__global__ __launch_bounds__(512, 2) void gemm_i8(
    const signed char* __restrict__ xq, const signed char* __restrict__ yq,
    const float* __restrict__ sx, const float* __restrict__ sy,
    const float* __restrict__ xsq, const float* __restrict__ ysq,
    float* __restrict__ out, int M, int N)
{
    __shared__ __align__(16) char lds[131072];   // 128 KiB

    const int ntm = M / BM;             // 16
    const int ntn = N / BN;             // 32
    const int bid = blockIdx.x;
    int tm, tn;
    if (ntm == 16 && ntn == 32) {
        int xcd = bid & 7, k = bid >> 3;            // 8x8-region XCD swizzle
        tm = (xcd >> 2) * 8 + (k >> 3);
        tn = (xcd & 3) * 8 + (k & 7);
    } else {
        tm = bid / ntn;
        tn = bid % ntn;
    }

    const int tid  = threadIdx.x;       // 512 threads = 8 waves
    const int wid  = tid >> 6;
    const int lane = tid & 63;
    const int wm   = wid >> 2;          // 0..1
    const int wn   = wid & 3;           // 0..3
    const int l15  = lane & 15;
    const int hi   = lane >> 4;         // 0..3
    const int s8   = lane & 7;

    // ---- staging: dest LINEAR (base + lane*16B); global source 16B-block
    // pre-permuted: cbs = (lane&7) ^ ((lane>>3)&7). 128-B rows (BK=128 i8):
    // byte-identical geometry to the verified bf16 kernel (conflicts = 0).
    const int r8  = lane >> 3;
    const int cbs = s8 ^ (r8 & 7);
    const signed char* aBase = xq + (size_t)(tm * BM + wid * 16 + r8) * KD + cbs * 16;
    const signed char* bBase = yq + (size_t)(tn * BN + wid * 16 + r8) * KD + cbs * 16;
    const int dstBase = wid * 2048 + lane * 16;

    // second 8-row chunk: +8 rows in global, +8*128 = +1024 BYTES in LDS.
    #define STAGE_A(kt, h) do {                                               \
        const signed char* g_ = aBase + (size_t)(h) * 128 * KD + (size_t)(kt) * 128; \
        char* d_ = &lds[((kt) & 1) * 32768 + (h) * 16384 + dstBase];          \
        gld16(g_, d_); gld16(g_ + 8 * KD, d_ + 1024);                         \
    } while (0)
    #define STAGE_B(kt, h) do {                                               \
        const signed char* g_ = bBase + (size_t)(h) * 128 * KD + (size_t)(kt) * 128; \
        char* d_ = &lds[65536 + ((kt) & 1) * 32768 + (h) * 16384 + dstBase];  \
        gld16(g_, d_); gld16(g_ + 8 * KD, d_ + 1024);                         \
    } while (0)

    // ---- fragment read offsets (bytes); phys 16B-block = (ks*4+hi) ^ s8 ----
    int aro[4], bro[2], xk[2];
    #pragma unroll
    for (int i = 0; i < 4; ++i) aro[i] = (wm * 64 + i * 16 + l15) * 128;
    #pragma unroll
    for (int j = 0; j < 2; ++j) bro[j] = (wn * 32 + j * 16 + l15) * 128;
    xk[0] = ((0 + hi) ^ s8) * 16;
    xk[1] = ((4 + hi) ^ s8) * 16;

    i32x4 acc[2][4][2][2] = {};     // [mq][i][nq][j]
    i32x4 aF[2][4];                 // [ks][i]   current A-half
    i32x4 bF[2][2][2];              // [nq][ks][j]  both B halves held

    #define MFMA_Q(mq, nq) do {                                              \
        _Pragma("unroll") for (int ks = 0; ks < 2; ++ks)                     \
        _Pragma("unroll") for (int i = 0; i < 4; ++i)                        \
        _Pragma("unroll") for (int j = 0; j < 2; ++j)                        \
            acc[mq][i][nq][j] = __builtin_amdgcn_mfma_i32_16x16x64_i8(       \
                aF[ks][i], bF[nq][ks][j], acc[mq][i][nq][j], 0, 0, 0);       \
    } while (0)

    // ---- prologue: FIFO A0(0),B0(0),A1(0),B1(0),A0(1),B0(1) ----
    STAGE_A(0, 0); STAGE_B(0, 0);
    STAGE_A(0, 1); STAGE_B(0, 1);
    STAGE_A(1, 0); STAGE_B(1, 0);
    asm volatile("s_waitcnt vmcnt(8)" ::: "memory");   // tile-0 A0,B0 resident
    BAR();

    for (int s = 0; s < NT; ++s) {
        const int ab = (s & 1) * 32768;
        const int bb = 65536 + ab;

        // ===== p0: quadrant (0,0) — read A-half0 (8) + B-half0 (4) =====
        #pragma unroll
        for (int ks = 0; ks < 2; ++ks) {
            #pragma unroll
            for (int i = 0; i < 4; ++i)
                aF[ks][i] = *(const i32x4*)&lds[ab + aro[i] + xk[ks]];
            #pragma unroll
            for (int j = 0; j < 2; ++j)
                bF[0][ks][j] = *(const i32x4*)&lds[bb + bro[j] + xk[ks]];
        }
        if (s + 1 < NT) STAGE_A(s + 1, 1);
        asm volatile("s_waitcnt lgkmcnt(8)" ::: "memory");
        BAR();
        LGKM0();
        __builtin_amdgcn_sched_barrier(0);
        __builtin_amdgcn_s_setprio(1);
        MFMA_Q(0, 0);
        __builtin_amdgcn_s_setprio(0);
        if (s < NT - 1) {
            asm volatile("s_waitcnt vmcnt(6)" ::: "memory");   // B1(s) resident
        } else {
            asm volatile("s_waitcnt vmcnt(0)" ::: "memory");
        }
        BAR();

        // ===== p1: quadrant (0,1) — read B-half1 (4) =====
        #pragma unroll
        for (int ks = 0; ks < 2; ++ks)
            #pragma unroll
            for (int j = 0; j < 2; ++j)
                bF[1][ks][j] = *(const i32x4*)&lds[bb + 16384 + bro[j] + xk[ks]];
        if (s + 1 < NT) STAGE_B(s + 1, 1);
        BAR();
        LGKM0();
        __builtin_amdgcn_sched_barrier(0);
        __builtin_amdgcn_s_setprio(1);
        MFMA_Q(0, 1);
        __builtin_amdgcn_s_setprio(0);
        BAR();

        // ===== p2: quadrant (1,0) — read A-half1 (8) =====
        #pragma unroll
        for (int ks = 0; ks < 2; ++ks)
            #pragma unroll
            for (int i = 0; i < 4; ++i)
                aF[ks][i] = *(const i32x4*)&lds[ab + 16384 + aro[i] + xk[ks]];
        if (s + 2 < NT) STAGE_A(s + 2, 0);
        BAR();
        LGKM0();
        __builtin_amdgcn_sched_barrier(0);
        __builtin_amdgcn_s_setprio(1);
        MFMA_Q(1, 0);
        __builtin_amdgcn_s_setprio(0);
        BAR();

        // ===== p3: quadrant (1,1) — no reads =====
        if (s + 2 < NT) STAGE_B(s + 2, 0);
        __builtin_amdgcn_s_setprio(1);
        MFMA_Q(1, 1);
        __builtin_amdgcn_s_setprio(0);
        if (s < NT - 2) {
            asm volatile("s_waitcnt vmcnt(8)" ::: "memory");   // A0,B0(s+1) resident
        } else if (s == NT - 2) {
            asm volatile("s_waitcnt vmcnt(4)" ::: "memory");
        }
        BAR();
    }

    // ---- epilogue: out = sx2[row]*sy[col]*dot - xsq[row] - ysq[col] ----
    // C/D layout (16x16): col = lane&15, row = (lane>>4)*4 + reg
    #pragma unroll
    for (int mq = 0; mq < 2; ++mq)
        #pragma unroll
        for (int i = 0; i < 4; ++i) {
            int r0 = tm * BM + mq * 128 + wm * 64 + i * 16 + hi * 4;
            #pragma unroll
            for (int nq = 0; nq < 2; ++nq)
                #pragma unroll
                for (int j = 0; j < 2; ++j) {
                    int c = tn * BN + nq * 128 + wn * 32 + j * 16 + l15;
                    float syv = sy[c];
                    float ysv = ysq[c];
                    #pragma unroll
                    for (int r = 0; r < 4; ++r) {
                        int row = r0 + r;
                        out[(size_t)row * N + c] =
                            sx[row] * syv * (float)acc[mq][i][nq][j][r]
                            - xsq[row] - ysv;
                    }
                }
        }
}

// ---------------- fallback (shape/ws mismatch): exact f32 -----------------
__global__ __launch_bounds__(256) void fallback_l2(
    const float* __restrict__ x, const float* __restrict__ y,
    float* __restrict__ out, int M, int N, int K)
{
    int tx = threadIdx.x & 15, ty = threadIdx.x >> 4;
    int row = blockIdx.y * 16 + ty;
    int col = blockIdx.x * 16 + tx;
    __shared__ float xs[16][17], ys[16][17];
    float s = 0.f;
    for (int k0 = 0; k0 < K; k0 += 16) {
        xs[ty][tx] = x[(size_t)row * K + k0 + tx];
        ys[ty][tx] = y[(size_t)(blockIdx.x * 16 + ty) * K + k0 + tx];
        __syncthreads();
        #pragma unroll
        for (int kk = 0; kk < 16; ++kk) {
            float d = xs[ty][kk] - ys[tx][kk];
            s += d * d;
        }
        __syncthreads();
    }
    out[(size_t)row * N + col] = -s;
}

extern "C" void kernel_launch(void* const* d_in, const int* in_sizes, int n_in,
                              void* d_out, int out_size, void* d_ws, size_t ws_size,
                              hipStream_t stream) {
    const float* x = (const float*)d_in[0];
    const float* y = (const float*)d_in[1];
    float* out = (float*)d_out;
    const int M = in_sizes[0] / KD;   // 4096
    const int N = in_sizes[1] / KD;   // 8192

    size_t need = (size_t)(M + N) * KD            // i8 matrices
                + (size_t)(M + N) * 2 * sizeof(float) + 256;
    if (ws_size >= need && M == 4096 && N == 8192) {
        char* w = (char*)d_ws;
        signed char* xq = (signed char*)w;
        signed char* yq = xq + (size_t)M * KD;
        float* sx  = (float*)(yq + (size_t)N * KD);
        float* sy  = sx + M;
        float* xsq = sy + N;
        float* ysq = xsq + M;

        prep_q<<<M + N, 256, 0, stream>>>(x, y, xq, yq, sx, sy, xsq, ysq, M, N);
        int grid = (M / BM) * (N / BN);   // 512
        gemm_i8<<<grid, 512, 0, stream>>>(xq, yq, sx, sy, xsq, ysq, out, M, N);
    } else {
        dim3 g(N / 16, M / 16);
        fallback_l2<<<g, 256, 0, stream>>>(x, y, out, M, N, KD);
    }
}